// Round 6
// baseline (12424.264 us; speedup 1.0000x reference)
//
#include <hip/hip_runtime.h>
#include <cstddef>

#define B_ 128
#define T_ 512
#define I_ 512
#define H_ 1024
#define TH_ (T_ * H_)
#define PSTR 257              // partial-buffer row stride (floats)
#define LDSN (32 * PSTR)      // 8224 floats = 32.9 KB (>= 8*1024 h-stage)

// async global->LDS, 16B per lane. LDS dest = wave-uniform base + lane*16.
__device__ __forceinline__ void gload_lds16(const float* g, float* l) {
    __builtin_amdgcn_global_load_lds(
        (const __attribute__((address_space(1))) unsigned int*)g,
        (__attribute__((address_space(3))) unsigned int*)l, 16, 0, 0);
}

// ---------------------------------------------------------------------------
// Kernel 1: xin = x @ Wi^T + bi -> out rnn_out region [B,T,H]. (unchanged,
// passed rounds 1,2,4)
// ---------------------------------------------------------------------------
__global__ __launch_bounds__(256) void k_input_gemm(
    const float* __restrict__ A, const float* __restrict__ W,
    const float* __restrict__ bi, float* __restrict__ C)
{
    const int nb = blockIdx.x;
    const int mb = blockIdx.y;
    const int tid = threadIdx.x;
    const int tx = tid & 15;
    const int ty = tid >> 4;

    __shared__ float As[16][132];
    __shared__ float Ws[16][132];

    float acc[8][8];
#pragma unroll
    for (int i = 0; i < 8; ++i)
#pragma unroll
        for (int j = 0; j < 8; ++j) acc[i][j] = 0.f;

    const float* Ab = A + (size_t)mb * 128 * I_;
    const float* Wb = W + (size_t)nb * 128 * I_;

    for (int kt = 0; kt < I_; kt += 16) {
        {
            const int r = tid >> 2;
            const int kq = (tid & 3) * 4;
            float4 v0 = *(const float4*)(Ab + (size_t)r * I_ + kt + kq);
            float4 v1 = *(const float4*)(Ab + (size_t)(r + 64) * I_ + kt + kq);
            As[kq + 0][r] = v0.x; As[kq + 1][r] = v0.y;
            As[kq + 2][r] = v0.z; As[kq + 3][r] = v0.w;
            As[kq + 0][r + 64] = v1.x; As[kq + 1][r + 64] = v1.y;
            As[kq + 2][r + 64] = v1.z; As[kq + 3][r + 64] = v1.w;
            float4 w0 = *(const float4*)(Wb + (size_t)r * I_ + kt + kq);
            float4 w1 = *(const float4*)(Wb + (size_t)(r + 64) * I_ + kt + kq);
            Ws[kq + 0][r] = w0.x; Ws[kq + 1][r] = w0.y;
            Ws[kq + 2][r] = w0.z; Ws[kq + 3][r] = w0.w;
            Ws[kq + 0][r + 64] = w1.x; Ws[kq + 1][r + 64] = w1.y;
            Ws[kq + 2][r + 64] = w1.z; Ws[kq + 3][r + 64] = w1.w;
        }
        __syncthreads();

#pragma unroll
        for (int kk = 0; kk < 16; ++kk) {
            float4 a0 = *(const float4*)&As[kk][ty * 8];
            float4 a1 = *(const float4*)&As[kk][ty * 8 + 4];
            float4 b0 = *(const float4*)&Ws[kk][tx * 8];
            float4 b1 = *(const float4*)&Ws[kk][tx * 8 + 4];
            float av[8] = {a0.x, a0.y, a0.z, a0.w, a1.x, a1.y, a1.z, a1.w};
            float bv[8] = {b0.x, b0.y, b0.z, b0.w, b1.x, b1.y, b1.z, b1.w};
#pragma unroll
            for (int i = 0; i < 8; ++i)
#pragma unroll
                for (int j = 0; j < 8; ++j) acc[i][j] += av[i] * bv[j];
        }
        __syncthreads();
    }

    const int n0 = nb * 128 + tx * 8;
    float4 bv0 = *(const float4*)(bi + n0);
    float4 bv1 = *(const float4*)(bi + n0 + 4);
#pragma unroll
    for (int i = 0; i < 8; ++i) {
        const size_t m = (size_t)mb * 128 + ty * 8 + i;
        float4 c0, c1;
        c0.x = acc[i][0] + bv0.x; c0.y = acc[i][1] + bv0.y;
        c0.z = acc[i][2] + bv0.z; c0.w = acc[i][3] + bv0.w;
        c1.x = acc[i][4] + bv1.x; c1.y = acc[i][5] + bv1.y;
        c1.z = acc[i][6] + bv1.z; c1.w = acc[i][7] + bv1.w;
        *(float4*)(C + m * H_ + n0) = c0;
        *(float4*)(C + m * H_ + n0 + 4) = c1;
    }
}

// ---------------------------------------------------------------------------
// Kernel 2: persistent recurrence. 512 blocks x 256 thr = 2 blocks/CU
// (LDS 32.9KB and 256-VGPR cap both allow exactly 2).
// Block: bt=bx&15 -> rows m0=8*bt; nt=bx>>4 (0..31) -> cols n0=32*nt.
// Group = 32 blocks sharing bt (bx = bt mod 16 => same XCD mod 8).
// Thread (c=tid&7, s=tid>>3): cols n0+c*4+j (j=0..3), k-slice
// k = jj*128 + s*4 + u (jj=0..7) -> full 0..1023 coverage, 32-way k-split.
// Per step: gload_lds h-stage -> 1024 FMA (acc[8][4], conflict-free b128
// broadcast reads) -> 32-deep LDS partial reduce -> fused epilogue ->
// proven atomicAdd group barrier.
// ---------------------------------------------------------------------------
__global__ __launch_bounds__(256, 2) void k_rnn(
    const float* __restrict__ Wh, const float* __restrict__ bh,
    const float* __restrict__ h0, float* __restrict__ out,
    unsigned* __restrict__ bar)
{
    __shared__ float lds[LDSN];   // union: h-stage [8][1024] / partials [32][PSTR]

    const int bx = blockIdx.x;
    const int bt = bx & 15;
    const int nt = bx >> 4;
    const int m0 = bt * 8;
    const int n0 = nt * 32;
    const int tid = threadIdx.x;
    const int w = tid >> 6;
    const int lane = tid & 63;
    const int c = tid & 7;          // col group (4 cols)
    const int s = tid >> 3;         // 0..31 k-phase (32-way split)

    // ---- one-time: Wh register-stationary: cols n0+c*4+j, k=jj*128+s*4 ----
    float4 wreg[4][8];
#pragma unroll
    for (int j = 0; j < 4; ++j) {
        const float* wp = Wh + (size_t)(n0 + c * 4 + j) * H_ + s * 4;
#pragma unroll
        for (int jj = 0; jj < 8; ++jj)
            wreg[j][jj] = *(const float4*)(wp + jj * 128);
    }

    const int r  = tid >> 5;         // output row 0..7
    const int nl = tid & 31;         // output col-local
    const float bh1 = bh[n0 + nl];
    unsigned* mybar = bar + bt * 32; // 128 B apart per group

    for (int t = 0; t < T_; ++t) {
        // ---- stage h_{t-1} rows m0..m0+7 into LDS via global_load_lds ----
        const float* hb; size_t rstr;
        if (t == 0) { hb = h0; rstr = 0; }
        else        { hb = out + (size_t)(t - 1) * H_; rstr = TH_; }
#pragma unroll
        for (int p = 0; p < 8; ++p) {
            const float* gp = hb + (size_t)(m0 + p) * rstr + w * 256 + lane * 4;
            gload_lds16(gp, &lds[p * 1024 + w * 256]);
        }
        // xin prefetch (own cell)
        const size_t g0 = (size_t)(m0 + r) * TH_ + (size_t)t * H_ + n0 + nl;
        const float xin1 = out[g0];

        asm volatile("s_waitcnt vmcnt(0)" ::: "memory");
        __syncthreads();

        // h_prev for epilogue (read before LDS reuse)
        const float hp1 = lds[r * 1024 + n0 + nl];

        // ---- compute: acc[m][j] over this thread's 32-k slice ----
        float acc[8][4];
#pragma unroll
        for (int m = 0; m < 8; ++m)
#pragma unroll
            for (int j = 0; j < 4; ++j) acc[m][j] = 0.f;

#pragma unroll
        for (int m = 0; m < 8; ++m) {
#pragma unroll
            for (int jj = 0; jj < 8; ++jj) {
                float4 h4 = *(const float4*)&lds[m * 1024 + jj * 128 + s * 4];
#pragma unroll
                for (int j = 0; j < 4; ++j) {
                    acc[m][j] += h4.x * wreg[j][jj].x;
                    acc[m][j] += h4.y * wreg[j][jj].y;
                    acc[m][j] += h4.z * wreg[j][jj].z;
                    acc[m][j] += h4.w * wreg[j][jj].w;
                }
            }
        }
        __syncthreads();   // h reads done; LDS becomes partial buffer

        // ---- partial write: part[s][m*32 + c*4 + j] ----
#pragma unroll
        for (int m = 0; m < 8; ++m)
#pragma unroll
            for (int j = 0; j < 4; ++j)
                lds[PSTR * s + m * 32 + c * 4 + j] = acc[m][j];
        __syncthreads();

        // ---- reduce over 32 k-phases: thread owns flat cell tid ----
        float red = 0.f;
#pragma unroll
        for (int g = 0; g < 32; ++g)
            red += lds[PSTR * g + tid];

        // ---- epilogue: pre = h + xin + Wh.h + bh; clamp [0,1] ----
        const float res = fminf(fmaxf(hp1 + xin1 + red + bh1, 0.f), 1.f);
        out[g0] = res;
        if (t == T_ - 1) {
            out[(size_t)B_ * TH_ + (size_t)(m0 + r) * H_ + n0 + nl] = res;
        }

        // ---- group barrier over 32 blocks sharing bt (proven pattern) ----
        __syncthreads();   // drains this block's stores before arrival
        if (tid == 0) {
            __threadfence();
            atomicAdd(mybar, 1u);
            const unsigned tgt = (unsigned)(t + 1) * 32u;
            while (__hip_atomic_load(mybar, __ATOMIC_RELAXED,
                                     __HIP_MEMORY_SCOPE_AGENT) < tgt) {
                __builtin_amdgcn_s_sleep(1);
            }
            __threadfence();
        }
        __syncthreads();
    }
}

extern "C" void kernel_launch(void* const* d_in, const int* in_sizes, int n_in,
                              void* d_out, int out_size, void* d_ws, size_t ws_size,
                              hipStream_t stream)
{
    const float* x  = (const float*)d_in[0];
    const float* Wi = (const float*)d_in[1];
    const float* bi = (const float*)d_in[2];
    const float* Wh = (const float*)d_in[3];
    const float* bh = (const float*)d_in[4];
    const float* h0 = (const float*)d_in[5];
    float* out = (float*)d_out;
    unsigned* bar = (unsigned*)d_ws;

    // zero barrier counters (16 groups * 128 B spacing = 2048 B)
    const size_t zn = ws_size < 2048 ? ws_size : 2048;
    hipMemsetAsync(d_ws, 0, zn, stream);

    // 1) xin = x @ Wi^T + bi -> out rnn_out region
    k_input_gemm<<<dim3(8, 512), 256, 0, stream>>>(x, Wi, bi, out);

    // 2) persistent recurrence: 512 blocks, 2/CU co-resident
    k_rnn<<<dim3(512), dim3(256), 0, stream>>>(Wh, bh, h0, out, bar);
}

// Round 7
// 5573.528 us; speedup vs baseline: 2.2292x; 2.2292x over previous
//
#include <hip/hip_runtime.h>
#include <cstddef>

#define B_ 128
#define T_ 512
#define I_ 512
#define H_ 1024
#define TH_ (T_ * H_)
#define PSTR 257              // partial-buffer row stride (floats)
#define LDSN (32 * PSTR)      // 8224 floats = 32.9 KB (>= 8*1024 h-stage)

// ---------------------------------------------------------------------------
// Kernel 1: xin = x @ Wi^T + bi -> out rnn_out region [B,T,H]. (unchanged,
// passed rounds 1,2,4,6)
// ---------------------------------------------------------------------------
__global__ __launch_bounds__(256) void k_input_gemm(
    const float* __restrict__ A, const float* __restrict__ W,
    const float* __restrict__ bi, float* __restrict__ C)
{
    const int nb = blockIdx.x;
    const int mb = blockIdx.y;
    const int tid = threadIdx.x;
    const int tx = tid & 15;
    const int ty = tid >> 4;

    __shared__ float As[16][132];
    __shared__ float Ws[16][132];

    float acc[8][8];
#pragma unroll
    for (int i = 0; i < 8; ++i)
#pragma unroll
        for (int j = 0; j < 8; ++j) acc[i][j] = 0.f;

    const float* Ab = A + (size_t)mb * 128 * I_;
    const float* Wb = W + (size_t)nb * 128 * I_;

    for (int kt = 0; kt < I_; kt += 16) {
        {
            const int r = tid >> 2;
            const int kq = (tid & 3) * 4;
            float4 v0 = *(const float4*)(Ab + (size_t)r * I_ + kt + kq);
            float4 v1 = *(const float4*)(Ab + (size_t)(r + 64) * I_ + kt + kq);
            As[kq + 0][r] = v0.x; As[kq + 1][r] = v0.y;
            As[kq + 2][r] = v0.z; As[kq + 3][r] = v0.w;
            As[kq + 0][r + 64] = v1.x; As[kq + 1][r + 64] = v1.y;
            As[kq + 2][r + 64] = v1.z; As[kq + 3][r + 64] = v1.w;
            float4 w0 = *(const float4*)(Wb + (size_t)r * I_ + kt + kq);
            float4 w1 = *(const float4*)(Wb + (size_t)(r + 64) * I_ + kt + kq);
            Ws[kq + 0][r] = w0.x; Ws[kq + 1][r] = w0.y;
            Ws[kq + 2][r] = w0.z; Ws[kq + 3][r] = w0.w;
            Ws[kq + 0][r + 64] = w1.x; Ws[kq + 1][r + 64] = w1.y;
            Ws[kq + 2][r + 64] = w1.z; Ws[kq + 3][r + 64] = w1.w;
        }
        __syncthreads();

#pragma unroll
        for (int kk = 0; kk < 16; ++kk) {
            float4 a0 = *(const float4*)&As[kk][ty * 8];
            float4 a1 = *(const float4*)&As[kk][ty * 8 + 4];
            float4 b0 = *(const float4*)&Ws[kk][tx * 8];
            float4 b1 = *(const float4*)&Ws[kk][tx * 8 + 4];
            float av[8] = {a0.x, a0.y, a0.z, a0.w, a1.x, a1.y, a1.z, a1.w};
            float bv[8] = {b0.x, b0.y, b0.z, b0.w, b1.x, b1.y, b1.z, b1.w};
#pragma unroll
            for (int i = 0; i < 8; ++i)
#pragma unroll
                for (int j = 0; j < 8; ++j) acc[i][j] += av[i] * bv[j];
        }
        __syncthreads();
    }

    const int n0 = nb * 128 + tx * 8;
    float4 bv0 = *(const float4*)(bi + n0);
    float4 bv1 = *(const float4*)(bi + n0 + 4);
#pragma unroll
    for (int i = 0; i < 8; ++i) {
        const size_t m = (size_t)mb * 128 + ty * 8 + i;
        float4 c0, c1;
        c0.x = acc[i][0] + bv0.x; c0.y = acc[i][1] + bv0.y;
        c0.z = acc[i][2] + bv0.z; c0.w = acc[i][3] + bv0.w;
        c1.x = acc[i][4] + bv1.x; c1.y = acc[i][5] + bv1.y;
        c1.z = acc[i][6] + bv1.z; c1.w = acc[i][7] + bv1.w;
        *(float4*)(C + m * H_ + n0) = c0;
        *(float4*)(C + m * H_ + n0 + 4) = c1;
    }
}

// ---------------------------------------------------------------------------
// Kernel 2: persistent recurrence, FENCE-FREE exchange.
// Geometry identical to round 6 (verified correct): 512 blocks x 256 thr,
// bt=bx&15 -> rows m0=8*bt; nt=bx>>4 -> cols n0=32*nt; group = 32 blocks
// sharing bt. Thread (c=tid&7, s=tid>>3): cols n0+c*4+j, k=jj*128+s*4+u.
// Visibility: h stores + group flags are system-scope relaxed atomics
// (write-through, no L2 maintenance); h stage reads are system-scope
// relaxed atomic loads (cache-bypass, read L3). Release order = vmcnt(0)
// before flag store. NO __threadfence anywhere, NO atomic RMW.
// ---------------------------------------------------------------------------
__global__ __launch_bounds__(256, 2) void k_rnn(
    const float* __restrict__ Wh, const float* __restrict__ bh,
    const float* __restrict__ h0, float* __restrict__ out,
    unsigned* __restrict__ bar)
{
    __shared__ float lds[LDSN];   // union: h-stage [8][1024] / partials [32][PSTR]

    const int bx = blockIdx.x;
    const int bt = bx & 15;
    const int nt = bx >> 4;
    const int m0 = bt * 8;
    const int n0 = nt * 32;
    const int tid = threadIdx.x;
    const int c = tid & 7;          // col group (4 cols)
    const int s = tid >> 3;         // 0..31 k-phase (32-way split)

    // ---- one-time: Wh register-stationary: cols n0+c*4+j, k=jj*128+s*4 ----
    float4 wreg[4][8];
#pragma unroll
    for (int j = 0; j < 4; ++j) {
        const float* wp = Wh + (size_t)(n0 + c * 4 + j) * H_ + s * 4;
#pragma unroll
        for (int jj = 0; jj < 8; ++jj)
            wreg[j][jj] = *(const float4*)(wp + jj * 128);
    }

    const int r  = tid >> 5;         // output row 0..7
    const int nl = tid & 31;         // output col-local
    const float bh1 = bh[n0 + nl];
    unsigned* grp = bar + bt * 32;   // 32 flag slots for this row-group

    for (int t = 0; t < T_; ++t) {
        // ---- stage h_{t-1} rows m0..m0+7 via system-scope (bypass) loads ----
        const float* hb; size_t rstr;
        if (t == 0) { hb = h0; rstr = 0; }
        else        { hb = out + (size_t)(t - 1) * H_; rstr = TH_; }

        unsigned long long stg[16];
#pragma unroll
        for (int i = 0; i < 16; ++i) {
            const int f = i * 256 + tid;      // float2 index 0..4095
            const int p = f >> 9;             // row 0..7 (512 float2/row)
            const int col2 = f & 511;
            const unsigned long long* gp = (const unsigned long long*)
                (hb + (size_t)(m0 + p) * rstr + (size_t)col2 * 2);
            stg[i] = __hip_atomic_load(gp, __ATOMIC_RELAXED,
                                       __HIP_MEMORY_SCOPE_SYSTEM);
        }
        // xin prefetch (own cell; plain cached load — gemm data, L3-resident)
        const size_t g0 = (size_t)(m0 + r) * TH_ + (size_t)t * H_ + n0 + nl;
        const float xin1 = out[g0];

#pragma unroll
        for (int i = 0; i < 16; ++i) {
            const int f = i * 256 + tid;
            const int p = f >> 9;
            const int col2 = f & 511;
            *(unsigned long long*)&lds[p * 1024 + col2 * 2] = stg[i];
        }
        __syncthreads();

        // h_prev for epilogue (read before LDS reuse)
        const float hp1 = lds[r * 1024 + n0 + nl];

        // ---- compute: acc[m][j] over this thread's 32-k slice ----
        float acc[8][4];
#pragma unroll
        for (int m = 0; m < 8; ++m)
#pragma unroll
            for (int j = 0; j < 4; ++j) acc[m][j] = 0.f;

#pragma unroll
        for (int m = 0; m < 8; ++m) {
#pragma unroll
            for (int jj = 0; jj < 8; ++jj) {
                float4 h4 = *(const float4*)&lds[m * 1024 + jj * 128 + s * 4];
#pragma unroll
                for (int j = 0; j < 4; ++j) {
                    acc[m][j] += h4.x * wreg[j][jj].x;
                    acc[m][j] += h4.y * wreg[j][jj].y;
                    acc[m][j] += h4.z * wreg[j][jj].z;
                    acc[m][j] += h4.w * wreg[j][jj].w;
                }
            }
        }
        __syncthreads();   // h reads done; LDS becomes partial buffer

        // ---- partial write: part[s][m*32 + c*4 + j] ----
#pragma unroll
        for (int m = 0; m < 8; ++m)
#pragma unroll
            for (int j = 0; j < 4; ++j)
                lds[PSTR * s + m * 32 + c * 4 + j] = acc[m][j];
        __syncthreads();

        // ---- reduce over 32 k-phases: thread owns flat cell tid ----
        float red = 0.f;
#pragma unroll
        for (int g = 0; g < 32; ++g)
            red += lds[PSTR * g + tid];

        // ---- epilogue: pre = h + xin + Wh.h + bh; clamp [0,1] ----
        const float res = fminf(fmaxf(hp1 + xin1 + red + bh1, 0.f), 1.f);
        // h store: write-through (system scope) so group peers read it from L3
        __hip_atomic_store(out + g0, res, __ATOMIC_RELAXED,
                           __HIP_MEMORY_SCOPE_SYSTEM);
        if (t == T_ - 1) {
            out[(size_t)B_ * TH_ + (size_t)(m0 + r) * H_ + n0 + nl] = res;
        }

        // ---- fence-free group barrier: release = vmcnt(0) + flag store ----
        asm volatile("s_waitcnt vmcnt(0)" ::: "memory");  // own stores done
        __syncthreads();                                   // whole block done
        if (tid == 0) {
            __hip_atomic_store(&grp[nt], (unsigned)(t + 1), __ATOMIC_RELAXED,
                               __HIP_MEMORY_SCOPE_SYSTEM);
        }
        if (tid < 64) {
            const unsigned tgt = (unsigned)(t + 1);
            for (;;) {
                unsigned v = __hip_atomic_load(&grp[tid & 31], __ATOMIC_RELAXED,
                                               __HIP_MEMORY_SCOPE_SYSTEM);
                if (__all(v >= tgt)) break;
                __builtin_amdgcn_s_sleep(1);
            }
        }
        __syncthreads();
    }
}

extern "C" void kernel_launch(void* const* d_in, const int* in_sizes, int n_in,
                              void* d_out, int out_size, void* d_ws, size_t ws_size,
                              hipStream_t stream)
{
    const float* x  = (const float*)d_in[0];
    const float* Wi = (const float*)d_in[1];
    const float* bi = (const float*)d_in[2];
    const float* Wh = (const float*)d_in[3];
    const float* bh = (const float*)d_in[4];
    const float* h0 = (const float*)d_in[5];
    float* out = (float*)d_out;
    unsigned* bar = (unsigned*)d_ws;

    // zero flag slots (16 groups * 32 slots * 4 B = 2048 B)
    const size_t zn = ws_size < 2048 ? ws_size : 2048;
    hipMemsetAsync(d_ws, 0, zn, stream);

    // 1) xin = x @ Wi^T + bi -> out rnn_out region
    k_input_gemm<<<dim3(8, 512), 256, 0, stream>>>(x, Wi, bi, out);

    // 2) persistent recurrence: 512 blocks, 2/CU co-resident
    k_rnn<<<dim3(512), dim3(256), 0, stream>>>(Wh, bh, h0, out, bar);
}

// Round 9
// 5556.432 us; speedup vs baseline: 2.2360x; 1.0031x over previous
//
#include <hip/hip_runtime.h>
#include <cstddef>

#define B_ 128
#define T_ 512
#define I_ 512
#define H_ 1024
#define TH_ (T_ * H_)
#define PSTR 257              // partial-buffer row stride (floats)
#define LDSN (32 * PSTR)      // 8224 floats = 32.9 KB
#define XBN (B_ * H_)         // exchange buffer: 131072 floats = 512 KB each

// ---------------------------------------------------------------------------
// Kernel 1: xin = x @ Wi^T + bi -> out rnn_out region [B,T,H]. (unchanged,
// passed rounds 1,2,4,6,7; ~143 TF fp32 ≈ 91% of vector peak)
// ---------------------------------------------------------------------------
__global__ __launch_bounds__(256) void k_input_gemm(
    const float* __restrict__ A, const float* __restrict__ W,
    const float* __restrict__ bi, float* __restrict__ C)
{
    const int nb = blockIdx.x;
    const int mb = blockIdx.y;
    const int tid = threadIdx.x;
    const int tx = tid & 15;
    const int ty = tid >> 4;

    __shared__ float As[16][132];
    __shared__ float Ws[16][132];

    float acc[8][8];
#pragma unroll
    for (int i = 0; i < 8; ++i)
#pragma unroll
        for (int j = 0; j < 8; ++j) acc[i][j] = 0.f;

    const float* Ab = A + (size_t)mb * 128 * I_;
    const float* Wb = W + (size_t)nb * 128 * I_;

    for (int kt = 0; kt < I_; kt += 16) {
        {
            const int r = tid >> 2;
            const int kq = (tid & 3) * 4;
            float4 v0 = *(const float4*)(Ab + (size_t)r * I_ + kt + kq);
            float4 v1 = *(const float4*)(Ab + (size_t)(r + 64) * I_ + kt + kq);
            As[kq + 0][r] = v0.x; As[kq + 1][r] = v0.y;
            As[kq + 2][r] = v0.z; As[kq + 3][r] = v0.w;
            As[kq + 0][r + 64] = v1.x; As[kq + 1][r + 64] = v1.y;
            As[kq + 2][r + 64] = v1.z; As[kq + 3][r + 64] = v1.w;
            float4 w0 = *(const float4*)(Wb + (size_t)r * I_ + kt + kq);
            float4 w1 = *(const float4*)(Wb + (size_t)(r + 64) * I_ + kt + kq);
            Ws[kq + 0][r] = w0.x; Ws[kq + 1][r] = w0.y;
            Ws[kq + 2][r] = w0.z; Ws[kq + 3][r] = w0.w;
            Ws[kq + 0][r + 64] = w1.x; Ws[kq + 1][r + 64] = w1.y;
            Ws[kq + 2][r + 64] = w1.z; Ws[kq + 3][r + 64] = w1.w;
        }
        __syncthreads();

#pragma unroll
        for (int kk = 0; kk < 16; ++kk) {
            float4 a0 = *(const float4*)&As[kk][ty * 8];
            float4 a1 = *(const float4*)&As[kk][ty * 8 + 4];
            float4 b0 = *(const float4*)&Ws[kk][tx * 8];
            float4 b1 = *(const float4*)&Ws[kk][tx * 8 + 4];
            float av[8] = {a0.x, a0.y, a0.z, a0.w, a1.x, a1.y, a1.z, a1.w};
            float bv[8] = {b0.x, b0.y, b0.z, b0.w, b1.x, b1.y, b1.z, b1.w};
#pragma unroll
            for (int i = 0; i < 8; ++i)
#pragma unroll
                for (int j = 0; j < 8; ++j) acc[i][j] += av[i] * bv[j];
        }
        __syncthreads();
    }

    const int n0 = nb * 128 + tx * 8;
    float4 bv0 = *(const float4*)(bi + n0);
    float4 bv1 = *(const float4*)(bi + n0 + 4);
#pragma unroll
    for (int i = 0; i < 8; ++i) {
        const size_t m = (size_t)mb * 128 + ty * 8 + i;
        float4 c0, c1;
        c0.x = acc[i][0] + bv0.x; c0.y = acc[i][1] + bv0.y;
        c0.z = acc[i][2] + bv0.z; c0.w = acc[i][3] + bv0.w;
        c1.x = acc[i][4] + bv1.x; c1.y = acc[i][5] + bv1.y;
        c1.z = acc[i][6] + bv1.z; c1.w = acc[i][7] + bv1.w;
        *(float4*)(C + m * H_ + n0) = c0;
        *(float4*)(C + m * H_ + n0 + 4) = c1;
    }
}

// step-t exchange offset: 8 or 12 alternating every 2 steps.
__device__ __forceinline__ float ofs_of(int t) {
    return 8.0f + 4.0f * (float)((t >> 1) & 1);
}

// ---------------------------------------------------------------------------
// Kernel 2: persistent recurrence with VALUE-CARRYING exchange (no flags,
// no fences, no barrier). Geometry = round-6/7 verified: 512 blocks x 256
// thr (2/CU, residency slack 4/CU); bt=bx&15 -> rows m0=8*bt; nt=bx>>4 ->
// cols n0=32*nt. Thread (c=tid&7, s=tid>>3): cols n0+c*4+j, k=jj*128+s*4+u.
// Exchange: producers store h+O(t) to xbuf[t&1] (system-scope write-through,
// fire-and-forget); consumers poll their 16 words with range check
// [O-0.5, O+1.5] and retry stale ones. Disjointness: h in [0,1] (clamp),
// O alternates 8/12, memset-0 per call kills cross-replay staleness;
// per-address coherence + the h_t->h_{t-1} full dependency make 2 offsets
// sufficient. Clean h goes to out via plain cached stores (owner-exclusive
// cells). Final hidden tail written at t=T-1.
// ---------------------------------------------------------------------------
__global__ __launch_bounds__(256, 2) void k_rnn(
    const float* __restrict__ Wh, const float* __restrict__ bh,
    const float* __restrict__ h0, float* __restrict__ out,
    float* __restrict__ xbuf)
{
    __shared__ float lds[LDSN];   // union: h-stage [8][1024] / partials [32][PSTR]

    const int bx = blockIdx.x;
    const int bt = bx & 15;
    const int nt = bx >> 4;
    const int m0 = bt * 8;
    const int n0 = nt * 32;
    const int tid = threadIdx.x;
    const int c = tid & 7;          // col group (4 cols)
    const int s = tid >> 3;         // 0..31 k-phase (32-way split)

    // ---- one-time: Wh register-stationary: cols n0+c*4+j, k=jj*128+s*4 ----
    float4 wreg[4][8];
#pragma unroll
    for (int j = 0; j < 4; ++j) {
        const float* wp = Wh + (size_t)(n0 + c * 4 + j) * H_ + s * 4;
#pragma unroll
        for (int jj = 0; jj < 8; ++jj)
            wreg[j][jj] = *(const float4*)(wp + jj * 128);
    }

    const int r  = tid >> 5;         // output row 0..7
    const int nl = tid & 31;         // output col-local
    const float bh1 = bh[n0 + nl];

    for (int t = 0; t < T_; ++t) {
        // xin prefetch (own cell; plain cached load)
        const size_t g0 = (size_t)(m0 + r) * TH_ + (size_t)t * H_ + n0 + nl;
        const float xin1 = out[g0];

        // ---- stage h_{t-1} rows m0..m0+7 into LDS ----
        if (t == 0) {
            // h0 broadcast (single row), no poll needed
#pragma unroll
            for (int i = 0; i < 16; ++i) {
                const int f = i * 256 + tid;
                const int p = f >> 9;
                const int col2 = f & 511;
                const unsigned long long v =
                    *(const unsigned long long*)(h0 + (size_t)col2 * 2);
                *(unsigned long long*)&lds[p * 1024 + col2 * 2] = v;
            }
        } else {
            const unsigned long long* xb = (const unsigned long long*)
                (xbuf + (size_t)((t - 1) & 1) * XBN);
            const float osub = ofs_of(t - 1);
            const float olo = osub - 0.5f;
            const float ohi = osub + 1.5f;

            unsigned long long stg[16];
#pragma unroll
            for (int i = 0; i < 16; ++i) {
                const int f = i * 256 + tid;
                const int p = f >> 9;
                const int col2 = f & 511;
                stg[i] = __hip_atomic_load(&xb[(size_t)(m0 + p) * 512 + col2],
                                           __ATOMIC_RELAXED,
                                           __HIP_MEMORY_SCOPE_SYSTEM);
            }
            for (;;) {
                unsigned bad = 0;
#pragma unroll
                for (int i = 0; i < 16; ++i) {
                    const float lo = __uint_as_float((unsigned)(stg[i] & 0xffffffffull));
                    const float hi = __uint_as_float((unsigned)(stg[i] >> 32));
                    const bool ok = (lo >= olo) & (lo <= ohi) &
                                    (hi >= olo) & (hi <= ohi);
                    if (!ok) bad |= (1u << i);
                }
                if (!bad) break;
#pragma unroll
                for (int i = 0; i < 16; ++i) {
                    if (bad & (1u << i)) {
                        const int f = i * 256 + tid;
                        const int p = f >> 9;
                        const int col2 = f & 511;
                        stg[i] = __hip_atomic_load(&xb[(size_t)(m0 + p) * 512 + col2],
                                                   __ATOMIC_RELAXED,
                                                   __HIP_MEMORY_SCOPE_SYSTEM);
                    }
                }
            }
            // subtract offset, write to LDS
#pragma unroll
            for (int i = 0; i < 16; ++i) {
                const int f = i * 256 + tid;
                const int p = f >> 9;
                const int col2 = f & 511;
                float lo = __uint_as_float((unsigned)(stg[i] & 0xffffffffull)) - osub;
                float hi = __uint_as_float((unsigned)(stg[i] >> 32)) - osub;
                float2 v; v.x = lo; v.y = hi;
                *(float2*)&lds[p * 1024 + col2 * 2] = v;
            }
        }
        __syncthreads();

        // h_prev for epilogue (read before LDS reuse)
        const float hp1 = lds[r * 1024 + n0 + nl];

        // ---- compute: acc[m][j] over this thread's 32-k slice ----
        float acc[8][4];
#pragma unroll
        for (int m = 0; m < 8; ++m)
#pragma unroll
            for (int j = 0; j < 4; ++j) acc[m][j] = 0.f;

#pragma unroll
        for (int m = 0; m < 8; ++m) {
#pragma unroll
            for (int jj = 0; jj < 8; ++jj) {
                float4 h4 = *(const float4*)&lds[m * 1024 + jj * 128 + s * 4];
#pragma unroll
                for (int j = 0; j < 4; ++j) {
                    acc[m][j] += h4.x * wreg[j][jj].x;
                    acc[m][j] += h4.y * wreg[j][jj].y;
                    acc[m][j] += h4.z * wreg[j][jj].z;
                    acc[m][j] += h4.w * wreg[j][jj].w;
                }
            }
        }
        __syncthreads();   // h reads done; LDS becomes partial buffer

        // ---- partial write: part[s][m*32 + c*4 + j] ----
#pragma unroll
        for (int m = 0; m < 8; ++m)
#pragma unroll
            for (int j = 0; j < 4; ++j)
                lds[PSTR * s + m * 32 + c * 4 + j] = acc[m][j];
        __syncthreads();

        // ---- reduce over 32 k-phases: thread owns flat cell tid ----
        float red = 0.f;
#pragma unroll
        for (int g = 0; g < 32; ++g)
            red += lds[PSTR * g + tid];

        // ---- epilogue: pre = h + xin + Wh.h + bh; clamp [0,1] ----
        const float res = fminf(fmaxf(hp1 + xin1 + red + bh1, 0.f), 1.f);
        out[g0] = res;                       // clean value, plain cached store
        if (t == T_ - 1) {
            out[(size_t)B_ * TH_ + (size_t)(m0 + r) * H_ + n0 + nl] = res;
        } else {
            // value-carrying exchange: fire-and-forget write-through store
            __hip_atomic_store(
                xbuf + (size_t)(t & 1) * XBN + (size_t)(m0 + r) * H_ + n0 + nl,
                res + ofs_of(t), __ATOMIC_RELAXED, __HIP_MEMORY_SCOPE_SYSTEM);
        }

        __syncthreads();   // reduce reads done before next step's LDS writes
    }
}

extern "C" void kernel_launch(void* const* d_in, const int* in_sizes, int n_in,
                              void* d_out, int out_size, void* d_ws, size_t ws_size,
                              hipStream_t stream)
{
    const float* x  = (const float*)d_in[0];
    const float* Wi = (const float*)d_in[1];
    const float* bi = (const float*)d_in[2];
    const float* Wh = (const float*)d_in[3];
    const float* bh = (const float*)d_in[4];
    const float* h0 = (const float*)d_in[5];
    float* out = (float*)d_out;
    float* xbuf = (float*)d_ws;

    // zero both exchange buffers (2 * 512 KB): kills cross-replay staleness
    const size_t need = (size_t)2 * XBN * sizeof(float);
    const size_t zn = ws_size < need ? ws_size : need;
    hipMemsetAsync(d_ws, 0, zn, stream);

    // 1) xin = x @ Wi^T + bi -> out rnn_out region
    k_input_gemm<<<dim3(8, 512), 256, 0, stream>>>(x, Wi, bi, out);

    // 2) persistent recurrence: 512 blocks, 2/CU (capacity 4 -> slack)
    k_rnn<<<dim3(512), dim3(256), 0, stream>>>(Wh, bh, h0, out, xbuf);
}